// Round 1
// baseline (1390.299 us; speedup 1.0000x reference)
//
#include <hip/hip_runtime.h>
#include <hip/hip_cooperative_groups.h>

namespace cg = cooperative_groups;

#define GX 432
#define GY 496
#define G_TOTAL (GX * GY) /* 214272, GZ=1 */
#define MAX_PTS 32
#define MAX_VOX 20000
#define CAP 64
#define INF_SENTINEL 0x7F7F7F7F
#define PREFIX_K 262144 /* ~133k in-range claims -> ~99k distinct cells >> 20000 */
#define NB 1024        /* cooperative grid: 4 blocks/CU x 256 CUs */
#define NT (NB * 256)  /* 262144 threads */

typedef unsigned long long u64;

struct Args {
    const float4* pts;
    int* lin;
    int* first;
    u64* isFirst64;
    u64* bits;
    unsigned* wordLocal;
    int* sums;
    int* rank;
    int* vcount;
    int* cellOfRank;
    int* dcount;
    int* list;
    float4* voxOut;
    float* coorsOut;
    float* npOut;
    float* nvOut;
    int W, K, n, nbW;
};

// IEEE float32 ops exactly matching the reference:
// c = floor((p - lo)/vs), lo = [0, -39.68, -3], vs = [.16,.16,4].
__device__ __forceinline__ int cell_of(float4 p, bool& ok) {
    float fx = floorf((p.x - 0.0f) / 0.16f);
    float fy = floorf((p.y + 39.68f) / 0.16f);
    float fz = floorf((p.z + 3.0f) / 4.0f);
    int cx = (int)fx, cy = (int)fy, cz = (int)fz;
    ok = (cx >= 0 && cx < GX && cy >= 0 && cy < GY && cz == 0);
    return cy * GX + cx;
}

// One cooperative kernel replacing the former 10-dispatch pipeline.
// Phases separated by grid.sync(); all producer->consumer hazards are
// cross-block, so each boundary gets __threadfence() (agent scope,
// cross-XCD visibility) + grid.sync().
__global__ __launch_bounds__(256, 4) void mega(Args a) {
    const int t = threadIdx.x;
    const int tid = blockIdx.x * 256 + t;
    cg::grid_group grid = cg::this_grid();

    __shared__ int red[4];
    __shared__ int wsum[4], wexc[4];
    __shared__ int s[4][CAP];
    __shared__ int slotPt[4][MAX_PTS];

    unsigned char* isFirstB = (unsigned char*)a.isFirst64;

    // ---- P0: all initializations (replaces hipMemsetAsync + fused inits)
    for (int c = tid; c < G_TOTAL; c += NT) {
        a.first[c] = INF_SENTINEL;
        a.rank[c] = INF_SENTINEL;
    }
    for (int w2 = tid; w2 < a.W * 8; w2 += NT) a.isFirst64[w2] = 0ull;
    if (tid < MAX_VOX) { a.vcount[tid] = -1; a.cellOfRank[tid] = -1; }
    if (tid == 0) *a.dcount = 0;
    __threadfence();
    grid.sync();

    // ---- P1: point pass — lin[] for all points, atomicMin claim for i < K.
    // 4-way unrolled grid-stride for memory-level parallelism.
    {
        const int n = a.n, K0 = a.K;
        int i = tid;
        for (; i + 3 * NT < n; i += 4 * NT) {
            float4 p0 = a.pts[i];
            float4 p1 = a.pts[i + NT];
            float4 p2 = a.pts[i + 2 * NT];
            float4 p3 = a.pts[i + 3 * NT];
            bool k0, k1, k2, k3;
            int c0 = cell_of(p0, k0);
            int c1 = cell_of(p1, k1);
            int c2 = cell_of(p2, k2);
            int c3 = cell_of(p3, k3);
            a.lin[i] = k0 ? c0 : -1;
            a.lin[i + NT] = k1 ? c1 : -1;
            a.lin[i + 2 * NT] = k2 ? c2 : -1;
            a.lin[i + 3 * NT] = k3 ? c3 : -1;
            if (k0 && i < K0) atomicMin(&a.first[c0], i);
            if (k1 && i + NT < K0) atomicMin(&a.first[c1], i + NT);
            if (k2 && i + 2 * NT < K0) atomicMin(&a.first[c2], i + 2 * NT);
            if (k3 && i + 3 * NT < K0) atomicMin(&a.first[c3], i + 3 * NT);
        }
        for (; i < n; i += NT) {
            float4 p = a.pts[i];
            bool ok;
            int c = cell_of(p, ok);
            a.lin[i] = ok ? c : -1;
            if (ok && i < K0) atomicMin(&a.first[c], i);
        }
    }
    __threadfence();
    grid.sync();

    // ---- P2: countD + markFirst fused (both only read first[]).
    // Distinct cells have distinct first indices -> byte stores race-free.
    {
        int have = 0;
        for (int c = tid; c < G_TOTAL; c += NT) {
            int f = a.first[c];
            if (f != INF_SENTINEL) {
                have++;
                isFirstB[f] = 1;
            }
        }
        for (int d = 32; d >= 1; d >>= 1) have += __shfl_down(have, d, 64);
        if ((t & 63) == 0) red[t >> 6] = have;
        __syncthreads();
        if (t == 0) atomicAdd(a.dcount, red[0] + red[1] + red[2] + red[3]);
    }
    __threadfence();
    grid.sync();

    // ---- P3: guard — only if prefix yielded < MAX_VOX distinct cells
    // (statistically never for this input). Branch is grid-uniform, so
    // grid.sync() inside is legal. Repairs first[] AND re-marks isFirst.
    {
        int dc = *a.dcount;
        if (dc < MAX_VOX) {
            for (int i = a.K + tid; i < a.n; i += NT) {
                float4 p = a.pts[i];
                bool ok;
                int c = cell_of(p, ok);
                if (ok && a.first[c] > i) atomicMin(&a.first[c], i);
            }
            __threadfence();
            grid.sync();
            for (int w2 = tid; w2 < a.W * 8; w2 += NT) a.isFirst64[w2] = 0ull;
            __threadfence();
            grid.sync();
            for (int c = tid; c < G_TOTAL; c += NT) {
                int f = a.first[c];
                if (f != INF_SENTINEL) isFirstB[f] = 1;
            }
            __threadfence();
            grid.sync();
        }
    }

    // ---- P4: scanA — pack bytes->bits, per-word local prefix, block sums.
    // One word per thread; blocks [0, nbW) participate (nbW = 123).
    if (blockIdx.x < a.nbW) {
        int wi = blockIdx.x * 256 + t;
        u64 mask = 0;
        if (wi < a.W) {
            const u64* src = a.isFirst64 + (size_t)wi * 8;
#pragma unroll
            for (int j = 0; j < 8; j++) {
                u64 chunk = src[j];  // 8 bytes, each 0 or 1
                u64 m8 = (chunk * 0x0102040810204080ull) >> 56;
                mask |= m8 << (8 * j);
            }
            a.bits[wi] = mask;
        }
        int v = __popcll(mask);
        int lane = t & 63, w = t >> 6;
        int x = v;
        for (int d = 1; d < 64; d <<= 1) {
            int y = __shfl_up(x, d, 64);
            if (lane >= d) x += y;
        }
        if (lane == 63) wsum[w] = x;
        __syncthreads();
        if (t == 0) {
            int acc = 0;
            for (int j = 0; j < 4; j++) { wexc[j] = acc; acc += wsum[j]; }
            a.sums[blockIdx.x] = acc;
        }
        __syncthreads();
        if (wi < a.W) a.wordLocal[wi] = (unsigned)(wexc[w] + x - v);
    }
    __threadfence();
    grid.sync();

    // ---- P5: scanB — exclusive scan of block sums (nbW <= 256), block 0.
    if (blockIdx.x == 0) {
        int v = (t < a.nbW) ? a.sums[t] : 0;
        int lane = t & 63, w = t >> 6;
        int x = v;
        for (int d = 1; d < 64; d <<= 1) {
            int y = __shfl_up(x, d, 64);
            if (lane >= d) x += y;
        }
        if (lane == 63) wsum[w] = x;
        __syncthreads();
        if (t == 0) {
            int acc = 0;
            for (int j = 0; j < 4; j++) { wexc[j] = acc; acc += wsum[j]; }
            a.nvOut[0] = (float)(acc < MAX_VOX ? acc : MAX_VOX);
        }
        __syncthreads();
        if (t < a.nbW) a.sums[t] = wexc[w] + x - v;
    }
    __threadfence();
    grid.sync();

    // ---- P6: rankCells — O(1) rank per claimed cell.
    for (int c = tid; c < G_TOTAL; c += NT) {
        int f = a.first[c];
        if (f == INF_SENTINEL) continue;
        int wf = f >> 6;
        int b = f & 63;
        u64 lowmask = (b == 0) ? 0ull : ((~0ull) >> (64 - b));
        int vr = a.sums[wf >> 8] + (int)a.wordLocal[wf] + __popcll(a.bits[wf] & lowmask);
        a.rank[c] = vr;
        if (vr < MAX_VOX) a.cellOfRank[vr] = c;
    }
    __threadfence();
    grid.sync();

    // ---- P7: append point indices into kept voxels' lists.
    for (int i = tid; i < a.n; i += NT) {
        int c = a.lin[i];
        if (c < 0) continue;
        int vr = a.rank[c];
        if (vr >= MAX_VOX) continue;
        int pos = atomicAdd(&a.vcount[vr], 1) + 1;
        if (pos < CAP) a.list[vr * CAP + pos] = i;
    }
    __threadfence();
    grid.sync();

    // ---- P8: finalize — counting-sort each voxel's list, write outputs.
    // 4 voxels per block-iteration (one wave each); grid-stride over 5000
    // virtual blocks. All LDS regions are per-wave, so loop reuse is safe.
    for (int vb = blockIdx.x; vb < MAX_VOX / 4; vb += NB) {
        int w = t >> 6, lane = t & 63;
        int v = vb * 4 + w;
        int cnt = a.vcount[v] + 1;
        int m = cnt < CAP ? cnt : CAP;
        s[w][lane] = (lane < m) ? a.list[v * CAP + lane] : 0x7FFFFFFF;
        if (lane < MAX_PTS) slotPt[w][lane] = -1;
        __syncthreads();
        int my = s[w][lane];
        int r = 0;
#pragma unroll
        for (int j = 0; j < CAP; j++) r += (s[w][j] < my) ? 1 : 0;  // broadcast
        if (lane < m && r < MAX_PTS) slotPt[w][r] = my;
        __syncthreads();
        if (lane < MAX_PTS) {
            int p = slotPt[w][lane];
            float4 val = make_float4(0.f, 0.f, 0.f, 0.f);
            if (p >= 0) val = a.pts[p];
            a.voxOut[(size_t)v * MAX_PTS + lane] = val;
        }
        if (lane == 0) {
            a.npOut[v] = (float)(cnt < MAX_PTS ? cnt : MAX_PTS);
            int cell = a.cellOfRank[v];
            if (cell < 0) {
                a.coorsOut[3 * v + 0] = -1.0f;
                a.coorsOut[3 * v + 1] = -1.0f;
                a.coorsOut[3 * v + 2] = -1.0f;
            } else {
                a.coorsOut[3 * v + 0] = 0.0f;  // cz (GZ==1)
                a.coorsOut[3 * v + 1] = (float)(cell / GX);
                a.coorsOut[3 * v + 2] = (float)(cell % GX);
            }
        }
        __syncthreads();
    }
}

extern "C" void kernel_launch(void* const* d_in, const int* in_sizes, int n_in,
                              void* d_out, int out_size, void* d_ws, size_t ws_size,
                              hipStream_t stream) {
    const float4* pts = (const float4*)d_in[0];
    int n = in_sizes[0] / 4;  // 2,000,000
    int W = (n + 63) >> 6;    // 31250 bitmap words
    int K = PREFIX_K < n ? PREFIX_K : n;
    int nbW = (W + 255) / 256;  // 123

    char* ws = (char*)d_ws;
    size_t off = 0;
    auto alloc = [&](size_t bytes) -> void* {
        void* p = (void*)(ws + off);
        off = (off + bytes + 255) & ~(size_t)255;
        return p;
    };
    int* first = (int*)alloc((size_t)G_TOTAL * 4);
    int* lin = (int*)alloc((size_t)n * 4);
    u64* isFirst64 = (u64*)alloc((size_t)W * 8 * 8);  // W*64 bytes
    u64* bits = (u64*)alloc((size_t)W * 8);
    unsigned* wordLocal = (unsigned*)alloc((size_t)W * 4);
    int* sums = (int*)alloc(256 * 4);
    int* rank = (int*)alloc((size_t)G_TOTAL * 4);
    int* vcount = (int*)alloc((size_t)MAX_VOX * 4);
    int* cellOfRank = (int*)alloc((size_t)MAX_VOX * 4);
    int* dcount = (int*)alloc(256 * 4);
    int* list = (int*)alloc((size_t)MAX_VOX * CAP * 4);
    (void)ws_size;
    (void)n_in;
    (void)out_size;

    float* out = (float*)d_out;
    float4* voxOut = (float4*)out;                          // 20000*32*4
    float* coorsOut = out + (size_t)MAX_VOX * MAX_PTS * 4;  // 20000*3
    float* npOut = coorsOut + (size_t)MAX_VOX * 3;          // 20000
    float* nvOut = npOut + MAX_VOX;                         // 1

    Args ha;
    ha.pts = pts;
    ha.lin = lin;
    ha.first = first;
    ha.isFirst64 = isFirst64;
    ha.bits = bits;
    ha.wordLocal = wordLocal;
    ha.sums = sums;
    ha.rank = rank;
    ha.vcount = vcount;
    ha.cellOfRank = cellOfRank;
    ha.dcount = dcount;
    ha.list = list;
    ha.voxOut = voxOut;
    ha.coorsOut = coorsOut;
    ha.npOut = npOut;
    ha.nvOut = nvOut;
    ha.W = W;
    ha.K = K;
    ha.n = n;
    ha.nbW = nbW;

    void* params[] = {&ha};
    hipLaunchCooperativeKernel((void*)mega, dim3(NB), dim3(256), params, 0,
                               stream);
}

// Round 2
// 152.670 us; speedup vs baseline: 9.1065x; 9.1065x over previous
//
#include <hip/hip_runtime.h>

#define GX 432
#define GY 496
#define G_TOTAL (GX * GY) /* 214272, GZ=1 */
#define MAX_PTS 32
#define MAX_VOX 20000
#define CAP 64
#define INF_SENTINEL 0x7F7F7F7F

typedef unsigned long long u64;

// IEEE float32 ops exactly matching the reference:
// c = floor((p - lo)/vs), lo = [0, -39.68, -3], vs = [.16,.16,4].
__device__ __forceinline__ int cell_of(float4 p, bool& ok) {
    float fx = floorf((p.x - 0.0f) / 0.16f);
    float fy = floorf((p.y + 39.68f) / 0.16f);
    float fz = floorf((p.z + 3.0f) / 4.0f);
    int cx = (int)fx, cy = (int)fy, cz = (int)fz;
    ok = (cx >= 0 && cx < GX && cy >= 0 && cy < GY && cz == 0);
    return cy * GX + cx;
}

// K1: fused initialization of every table consumed downstream.
__global__ __launch_bounds__(256) void kInit(int* __restrict__ first,
                                             u64* __restrict__ bits,
                                             int* __restrict__ vcount,
                                             int* __restrict__ cellOfRank,
                                             int W) {
    int i = blockIdx.x * 256 + threadIdx.x;
    if (i < G_TOTAL) first[i] = INF_SENTINEL;
    if (i < W) bits[i] = 0ull;
    if (i < MAX_VOX) { vcount[i] = -1; cellOfRank[i] = -1; }
}

// K2: point pass — lin[] store + filtered atomicMin claim for ALL in-range
// points. Filter is exact under stale reads: first[] only decreases, so a
// stale value is >= current; skipping when stale <= i implies current <= i,
// i.e. the atomicMin would be a no-op. No prefix heuristic, no guard needed.
__global__ __launch_bounds__(256) void kPoints(const float4* __restrict__ pts,
                                               int* __restrict__ lin,
                                               int* __restrict__ first,
                                               int n) {
    int i = blockIdx.x * 256 + threadIdx.x;
    if (i >= n) return;
    float4 p = pts[i];
    bool ok;
    int c = cell_of(p, ok);
    lin[i] = ok ? c : -1;
    if (ok && first[c] > i) atomicMin(&first[c], i);
}

// K3: set bit first[c] in the index-space bitmap. Distinct cells have
// distinct first indices; words shared by ~3 cells -> low-contention atomicOr.
__global__ __launch_bounds__(256) void kMark(const int* __restrict__ first,
                                             u64* __restrict__ bits) {
    int c = blockIdx.x * 256 + threadIdx.x;
    if (c >= G_TOTAL) return;
    int f = first[c];
    if (f != INF_SENTINEL) atomicOr(&bits[f >> 6], 1ull << (f & 63));
}

// K4: per-word intra-block exclusive prefix (wordLocal) + per-block sums.
// One 64-bit word per thread, 256 words per block.
__global__ __launch_bounds__(256) void kScan(const u64* __restrict__ bits,
                                             unsigned* __restrict__ wordLocal,
                                             int* __restrict__ sums, int W) {
    __shared__ int wsum[4], wexc[4];
    int t = threadIdx.x;
    int wi = blockIdx.x * 256 + t;
    u64 mask = (wi < W) ? bits[wi] : 0ull;
    int v = __popcll(mask);
    int lane = t & 63, w = t >> 6;
    int x = v;
    for (int d = 1; d < 64; d <<= 1) {
        int y = __shfl_up(x, d, 64);
        if (lane >= d) x += y;
    }
    if (lane == 63) wsum[w] = x;
    __syncthreads();
    if (t == 0) {
        int a = 0;
        for (int j = 0; j < 4; j++) { wexc[j] = a; a += wsum[j]; }
        sums[blockIdx.x] = a;
    }
    __syncthreads();
    if (wi < W) wordLocal[wi] = (unsigned)(wexc[w] + x - v);
}

// K5: append pass with INLINE rank computation. Each block redundantly
// exclusive-scans the (<=256) block sums in LDS (~500B, L2-hot), then each
// point computes its voxel rank in O(1): block base + word-local prefix +
// popcount of low bits. The point whose index equals first[c] also records
// cellOfRank. Block 0 writes num_voxels. Replaces former kScanB + rankCells
// + pass5 (and the rank[] array entirely).
__global__ __launch_bounds__(256) void kAppend(const int* __restrict__ lin,
                                               const int* __restrict__ first,
                                               const u64* __restrict__ bits,
                                               const unsigned* __restrict__ wordLocal,
                                               const int* __restrict__ sums,
                                               int nbW,
                                               int* __restrict__ vcount,
                                               int* __restrict__ cellOfRank,
                                               int* __restrict__ list,
                                               float* __restrict__ nvOut,
                                               int n) {
    __shared__ int sExc[256];
    __shared__ int wsum[4], wexc[4];
    int t = threadIdx.x;
    int v = (t < nbW) ? sums[t] : 0;
    int lane = t & 63, w = t >> 6;
    int x = v;
    for (int d = 1; d < 64; d <<= 1) {
        int y = __shfl_up(x, d, 64);
        if (lane >= d) x += y;
    }
    if (lane == 63) wsum[w] = x;
    __syncthreads();
    if (t == 0) {
        int a = 0;
        for (int j = 0; j < 4; j++) { wexc[j] = a; a += wsum[j]; }
        if (blockIdx.x == 0) nvOut[0] = (float)(a < MAX_VOX ? a : MAX_VOX);
    }
    __syncthreads();
    sExc[t] = wexc[w] + x - v;
    __syncthreads();

    int i = blockIdx.x * 256 + t;
    if (i >= n) return;
    int c = lin[i];
    if (c < 0) return;
    int f = first[c];
    int wf = f >> 6, b = f & 63;
    u64 lowmask = (b == 0) ? 0ull : ((~0ull) >> (64 - b));
    int vr = sExc[wf >> 8] + (int)wordLocal[wf] + __popcll(bits[wf] & lowmask);
    if (vr >= MAX_VOX) return;
    int pos = atomicAdd(&vcount[vr], 1) + 1;
    if (pos < CAP) list[vr * CAP + pos] = i;
    if (f == i) cellOfRank[vr] = c;
}

// K6: 4 voxels per 256-thread block (one wave each). Counting-sort the
// collected indices (LDS broadcast reads), write all 32 slots + num_points
// + coors (so no d_out pre-memset is needed).
__global__ __launch_bounds__(256) void passF(const float4* __restrict__ pts,
                                             const int* __restrict__ vcount,
                                             const int* __restrict__ cellOfRank,
                                             const int* __restrict__ list,
                                             float4* __restrict__ voxOut,
                                             float* __restrict__ coorsOut,
                                             float* __restrict__ npOut) {
    __shared__ int s[4][CAP];
    __shared__ int slotPt[4][MAX_PTS];
    int w = threadIdx.x >> 6, lane = threadIdx.x & 63;
    int v = blockIdx.x * 4 + w;
    int cnt = vcount[v] + 1;
    int m = cnt < CAP ? cnt : CAP;
    s[w][lane] = (lane < m) ? list[v * CAP + lane] : 0x7FFFFFFF;
    if (lane < MAX_PTS) slotPt[w][lane] = -1;
    __syncthreads();
    int my = s[w][lane];
    int r = 0;
#pragma unroll
    for (int j = 0; j < CAP; j++) r += (s[w][j] < my) ? 1 : 0;  // broadcast
    if (lane < m && r < MAX_PTS) slotPt[w][r] = my;
    __syncthreads();
    if (lane < MAX_PTS) {
        int p = slotPt[w][lane];
        float4 val = make_float4(0.f, 0.f, 0.f, 0.f);
        if (p >= 0) val = pts[p];
        voxOut[(size_t)v * MAX_PTS + lane] = val;
    }
    if (lane == 0) {
        npOut[v] = (float)(cnt < MAX_PTS ? cnt : MAX_PTS);
        int cell = cellOfRank[v];
        if (cell < 0) {
            coorsOut[3 * v + 0] = -1.0f;
            coorsOut[3 * v + 1] = -1.0f;
            coorsOut[3 * v + 2] = -1.0f;
        } else {
            coorsOut[3 * v + 0] = 0.0f;  // cz (GZ==1)
            coorsOut[3 * v + 1] = (float)(cell / GX);
            coorsOut[3 * v + 2] = (float)(cell % GX);
        }
    }
}

extern "C" void kernel_launch(void* const* d_in, const int* in_sizes, int n_in,
                              void* d_out, int out_size, void* d_ws, size_t ws_size,
                              hipStream_t stream) {
    const float4* pts = (const float4*)d_in[0];
    int n = in_sizes[0] / 4;    // 2,000,000
    int W = (n + 63) >> 6;      // 31250 bitmap words
    int nbW = (W + 255) / 256;  // 123

    char* ws = (char*)d_ws;
    size_t off = 0;
    auto alloc = [&](size_t bytes) -> void* {
        void* p = (void*)(ws + off);
        off = (off + bytes + 255) & ~(size_t)255;
        return p;
    };
    int* first = (int*)alloc((size_t)G_TOTAL * 4);
    int* lin = (int*)alloc((size_t)n * 4);
    u64* bits = (u64*)alloc((size_t)W * 8);
    unsigned* wordLocal = (unsigned*)alloc((size_t)W * 4);
    int* sums = (int*)alloc(256 * 4);
    int* vcount = (int*)alloc((size_t)MAX_VOX * 4);
    int* cellOfRank = (int*)alloc((size_t)MAX_VOX * 4);
    int* list = (int*)alloc((size_t)MAX_VOX * CAP * 4);
    (void)ws_size;
    (void)n_in;
    (void)out_size;

    float* out = (float*)d_out;
    float4* voxOut = (float4*)out;                          // 20000*32*4
    float* coorsOut = out + (size_t)MAX_VOX * MAX_PTS * 4;  // 20000*3
    float* npOut = coorsOut + (size_t)MAX_VOX * 3;          // 20000
    float* nvOut = npOut + MAX_VOX;                         // 1

    int nbP = (n + 255) / 256;        // 7813
    int nbC = (G_TOTAL + 255) / 256;  // 837

    kInit<<<nbC, 256, 0, stream>>>(first, bits, vcount, cellOfRank, W);
    kPoints<<<nbP, 256, 0, stream>>>(pts, lin, first, n);
    kMark<<<nbC, 256, 0, stream>>>(first, bits);
    kScan<<<nbW, 256, 0, stream>>>(bits, wordLocal, sums, W);
    kAppend<<<nbP, 256, 0, stream>>>(lin, first, bits, wordLocal, sums, nbW,
                                     vcount, cellOfRank, list, nvOut, n);
    passF<<<MAX_VOX / 4, 256, 0, stream>>>(pts, vcount, cellOfRank, list,
                                           voxOut, coorsOut, npOut);
}

// Round 3
// 152.363 us; speedup vs baseline: 9.1249x; 1.0020x over previous
//
#include <hip/hip_runtime.h>

#define GX 432
#define GY 496
#define G_TOTAL (GX * GY) /* 214272, GZ=1 */
#define MAX_PTS 32
#define MAX_VOX 20000
#define CAP 64
#define INF_SENTINEL 0x7F7F7F7F

typedef unsigned long long u64;

// IEEE float32 ops exactly matching the reference:
// c = floor((p - lo)/vs), lo = [0, -39.68, -3], vs = [.16,.16,4].
__device__ __forceinline__ int cell_of(float4 p, bool& ok) {
    float fx = floorf((p.x - 0.0f) / 0.16f);
    float fy = floorf((p.y + 39.68f) / 0.16f);
    float fz = floorf((p.z + 3.0f) / 4.0f);
    int cx = (int)fx, cy = (int)fy, cz = (int)fz;
    ok = (cx >= 0 && cx < GX && cy >= 0 && cy < GY && cz == 0);
    return cy * GX + cx;
}

// K1: fused initialization of every table consumed downstream.
__global__ __launch_bounds__(256) void kInit(int* __restrict__ first,
                                             u64* __restrict__ bits,
                                             int* __restrict__ vcount,
                                             int* __restrict__ cellOfRank,
                                             int W) {
    int i = blockIdx.x * 256 + threadIdx.x;
    if (i < G_TOTAL) first[i] = INF_SENTINEL;
    if (i < W) bits[i] = 0ull;
    if (i < MAX_VOX) { vcount[i] = -1; cellOfRank[i] = -1; }
}

// K2: point pass — lin[] store + UNCONDITIONAL fire-and-forget atomicMin for
// every in-range point. No read-filter (round-2 lesson: the dependent random
// load of first[c] made this pass latency-bound at 1.4 TB/s). Return value
// unused -> no-return atomic -> no waitcnt, pure streaming + ~1M memory-side
// atomics into an 857 KB table. first[] is EXACT afterwards: no prefix
// heuristic, no countD, no guard kernels needed for any input.
__global__ __launch_bounds__(256) void kPoints(const float4* __restrict__ pts,
                                               int* __restrict__ lin,
                                               int* __restrict__ first,
                                               int n) {
    int i = blockIdx.x * 256 + threadIdx.x;
    if (i >= n) return;
    float4 p = pts[i];
    bool ok;
    int c = cell_of(p, ok);
    lin[i] = ok ? c : -1;
    if (ok) atomicMin(&first[c], i);
}

// K3: set bit first[c] in the index-space bitmap. Distinct cells have
// distinct first indices; words shared by ~3 cells -> low-contention atomicOr.
__global__ __launch_bounds__(256) void kMark(const int* __restrict__ first,
                                             u64* __restrict__ bits) {
    int c = blockIdx.x * 256 + threadIdx.x;
    if (c >= G_TOTAL) return;
    int f = first[c];
    if (f != INF_SENTINEL) atomicOr(&bits[f >> 6], 1ull << (f & 63));
}

// K4: per-word intra-block exclusive prefix (wordLocal) + per-block sums.
// One 64-bit word per thread, 256 words per block.
__global__ __launch_bounds__(256) void kScan(const u64* __restrict__ bits,
                                             unsigned* __restrict__ wordLocal,
                                             int* __restrict__ sums, int W) {
    __shared__ int wsum[4], wexc[4];
    int t = threadIdx.x;
    int wi = blockIdx.x * 256 + t;
    u64 mask = (wi < W) ? bits[wi] : 0ull;
    int v = __popcll(mask);
    int lane = t & 63, w = t >> 6;
    int x = v;
    for (int d = 1; d < 64; d <<= 1) {
        int y = __shfl_up(x, d, 64);
        if (lane >= d) x += y;
    }
    if (lane == 63) wsum[w] = x;
    __syncthreads();
    if (t == 0) {
        int a = 0;
        for (int j = 0; j < 4; j++) { wexc[j] = a; a += wsum[j]; }
        sums[blockIdx.x] = a;
    }
    __syncthreads();
    if (wi < W) wordLocal[wi] = (unsigned)(wexc[w] + x - v);
}

// K5: materialize rank PER CELL (one O(1) computation per claimed cell, so
// the 2M-point append pass does only ONE random read). Each block redundantly
// exclusive-scans the (<=256) block sums in LDS (~500B, L2-hot). Also writes
// cellOfRank and num_voxels (block 0) — replaces the former kScanB.
__global__ __launch_bounds__(256) void kRank(const int* __restrict__ first,
                                             const u64* __restrict__ bits,
                                             const unsigned* __restrict__ wordLocal,
                                             const int* __restrict__ sums,
                                             int nbW,
                                             int* __restrict__ rank,
                                             int* __restrict__ cellOfRank,
                                             float* __restrict__ nvOut) {
    __shared__ int sExc[256];
    __shared__ int wsum[4], wexc[4];
    int t = threadIdx.x;
    int v = (t < nbW) ? sums[t] : 0;
    int lane = t & 63, w = t >> 6;
    int x = v;
    for (int d = 1; d < 64; d <<= 1) {
        int y = __shfl_up(x, d, 64);
        if (lane >= d) x += y;
    }
    if (lane == 63) wsum[w] = x;
    __syncthreads();
    if (t == 0) {
        int a = 0;
        for (int j = 0; j < 4; j++) { wexc[j] = a; a += wsum[j]; }
        if (blockIdx.x == 0) nvOut[0] = (float)(a < MAX_VOX ? a : MAX_VOX);
    }
    __syncthreads();
    sExc[t] = wexc[w] + x - v;
    __syncthreads();

    int c = blockIdx.x * 256 + t;
    if (c >= G_TOTAL) return;
    int f = first[c];
    if (f == INF_SENTINEL) return;
    int wf = f >> 6, b = f & 63;
    u64 lowmask = (b == 0) ? 0ull : ((~0ull) >> (64 - b));
    int vr = sExc[wf >> 8] + (int)wordLocal[wf] + __popcll(bits[wf] & lowmask);
    rank[c] = vr;  // only claimed cells written; only claimed cells read later
    if (vr < MAX_VOX) cellOfRank[vr] = c;
}

// K6: append pass — coalesced lin[i] + ONE random L2 read (rank[c]) + one
// fire-and-forget-ish atomic. ~95k appends total (kept voxels only).
__global__ __launch_bounds__(256) void kAppend(const int* __restrict__ lin,
                                               const int* __restrict__ rank,
                                               int* __restrict__ vcount,
                                               int* __restrict__ list, int n) {
    int i = blockIdx.x * 256 + threadIdx.x;
    if (i >= n) return;
    int c = lin[i];
    if (c < 0) return;
    int vr = rank[c];
    if (vr >= MAX_VOX) return;
    int pos = atomicAdd(&vcount[vr], 1) + 1;
    if (pos < CAP) list[vr * CAP + pos] = i;
}

// K7: 4 voxels per 256-thread block (one wave each). Counting-sort the
// collected indices (LDS broadcast reads), write all 32 slots + num_points
// + coors (so no d_out pre-memset is needed).
__global__ __launch_bounds__(256) void passF(const float4* __restrict__ pts,
                                             const int* __restrict__ vcount,
                                             const int* __restrict__ cellOfRank,
                                             const int* __restrict__ list,
                                             float4* __restrict__ voxOut,
                                             float* __restrict__ coorsOut,
                                             float* __restrict__ npOut) {
    __shared__ int s[4][CAP];
    __shared__ int slotPt[4][MAX_PTS];
    int w = threadIdx.x >> 6, lane = threadIdx.x & 63;
    int v = blockIdx.x * 4 + w;
    int cnt = vcount[v] + 1;
    int m = cnt < CAP ? cnt : CAP;
    s[w][lane] = (lane < m) ? list[v * CAP + lane] : 0x7FFFFFFF;
    if (lane < MAX_PTS) slotPt[w][lane] = -1;
    __syncthreads();
    int my = s[w][lane];
    int r = 0;
#pragma unroll
    for (int j = 0; j < CAP; j++) r += (s[w][j] < my) ? 1 : 0;  // broadcast
    if (lane < m && r < MAX_PTS) slotPt[w][r] = my;
    __syncthreads();
    if (lane < MAX_PTS) {
        int p = slotPt[w][lane];
        float4 val = make_float4(0.f, 0.f, 0.f, 0.f);
        if (p >= 0) val = pts[p];
        voxOut[(size_t)v * MAX_PTS + lane] = val;
    }
    if (lane == 0) {
        npOut[v] = (float)(cnt < MAX_PTS ? cnt : MAX_PTS);
        int cell = cellOfRank[v];
        if (cell < 0) {
            coorsOut[3 * v + 0] = -1.0f;
            coorsOut[3 * v + 1] = -1.0f;
            coorsOut[3 * v + 2] = -1.0f;
        } else {
            coorsOut[3 * v + 0] = 0.0f;  // cz (GZ==1)
            coorsOut[3 * v + 1] = (float)(cell / GX);
            coorsOut[3 * v + 2] = (float)(cell % GX);
        }
    }
}

extern "C" void kernel_launch(void* const* d_in, const int* in_sizes, int n_in,
                              void* d_out, int out_size, void* d_ws, size_t ws_size,
                              hipStream_t stream) {
    const float4* pts = (const float4*)d_in[0];
    int n = in_sizes[0] / 4;    // 2,000,000
    int W = (n + 63) >> 6;      // 31250 bitmap words
    int nbW = (W + 255) / 256;  // 123

    char* ws = (char*)d_ws;
    size_t off = 0;
    auto alloc = [&](size_t bytes) -> void* {
        void* p = (void*)(ws + off);
        off = (off + bytes + 255) & ~(size_t)255;
        return p;
    };
    int* first = (int*)alloc((size_t)G_TOTAL * 4);
    int* lin = (int*)alloc((size_t)n * 4);
    u64* bits = (u64*)alloc((size_t)W * 8);
    unsigned* wordLocal = (unsigned*)alloc((size_t)W * 4);
    int* sums = (int*)alloc(256 * 4);
    int* rank = (int*)alloc((size_t)G_TOTAL * 4);
    int* vcount = (int*)alloc((size_t)MAX_VOX * 4);
    int* cellOfRank = (int*)alloc((size_t)MAX_VOX * 4);
    int* list = (int*)alloc((size_t)MAX_VOX * CAP * 4);
    (void)ws_size;
    (void)n_in;
    (void)out_size;

    float* out = (float*)d_out;
    float4* voxOut = (float4*)out;                          // 20000*32*4
    float* coorsOut = out + (size_t)MAX_VOX * MAX_PTS * 4;  // 20000*3
    float* npOut = coorsOut + (size_t)MAX_VOX * 3;          // 20000
    float* nvOut = npOut + MAX_VOX;                         // 1

    int nbP = (n + 255) / 256;        // 7813
    int nbC = (G_TOTAL + 255) / 256;  // 837

    kInit<<<nbC, 256, 0, stream>>>(first, bits, vcount, cellOfRank, W);
    kPoints<<<nbP, 256, 0, stream>>>(pts, lin, first, n);
    kMark<<<nbC, 256, 0, stream>>>(first, bits);
    kScan<<<nbW, 256, 0, stream>>>(bits, wordLocal, sums, W);
    kRank<<<nbC, 256, 0, stream>>>(first, bits, wordLocal, sums, nbW, rank,
                                   cellOfRank, nvOut);
    kAppend<<<nbP, 256, 0, stream>>>(lin, rank, vcount, list, n);
    passF<<<MAX_VOX / 4, 256, 0, stream>>>(pts, vcount, cellOfRank, list,
                                           voxOut, coorsOut, npOut);
}